// Round 1
// baseline (825.416 us; speedup 1.0000x reference)
//
#include <hip/hip_runtime.h>

#define NUM_USERS 100000
#define NUM_ITEMS 200000
#define NUM_FEAT  64
#define NUM_EDGES 1000000
#define NN        (NUM_USERS + NUM_ITEMS)   // 300000

// ---- concat user||item into feat, and also init acc (=d_out) ----
__global__ void concat_init(const float* __restrict__ user,
                            const float* __restrict__ item,
                            float4* __restrict__ feat,
                            float4* __restrict__ acc) {
    const size_t total4 = (size_t)NN * NUM_FEAT / 4;        // 4.8M
    size_t i = (size_t)blockIdx.x * blockDim.x + threadIdx.x;
    if (i >= total4) return;
    const size_t ub4 = (size_t)NUM_USERS * NUM_FEAT / 4;    // 1.6M
    float4 v = (i < ub4) ? ((const float4*)user)[i]
                         : ((const float4*)item)[i - ub4];
    feat[i] = v;
    acc[i]  = v;
}

// ---- SpMM: one wave (64 lanes) per edge, lane = feature ----
__global__ void spmm_atomic(const int*   __restrict__ rows,
                            const int*   __restrict__ cols,
                            const float* __restrict__ vals,
                            const float* __restrict__ feat,
                            float*       __restrict__ out) {
    int t = blockIdx.x * blockDim.x + threadIdx.x;
    int e = t >> 6;           // edge index
    int f = t & 63;           // feature index (lane)
    if (e >= NUM_EDGES) return;
    int   r = rows[e];
    int   c = cols[e];
    float v = vals[e];
    float m = v * feat[(size_t)c * NUM_FEAT + f];
    atomicAdd(out + (size_t)r * NUM_FEAT + f, m);
}

// ---- acc += next (float4) ----
__global__ void acc_add(float4* __restrict__ acc, const float4* __restrict__ next) {
    const size_t total4 = (size_t)NN * NUM_FEAT / 4;
    size_t i = (size_t)blockIdx.x * blockDim.x + threadIdx.x;
    if (i >= total4) return;
    float4 a = acc[i];
    float4 n = next[i];
    a.x += n.x; a.y += n.y; a.z += n.z; a.w += n.w;
    acc[i] = a;
}

extern "C" void kernel_launch(void* const* d_in, const int* in_sizes, int n_in,
                              void* d_out, int out_size, void* d_ws, size_t ws_size,
                              hipStream_t stream) {
    const float* user = (const float*)d_in[0];
    const float* item = (const float*)d_in[1];
    const int*   rows = (const int*)d_in[2];
    const int*   cols = (const int*)d_in[3];
    const float* vals = (const float*)d_in[4];

    float* acc = (float*)d_out;                       // N x 64 fp32, users||items

    const size_t fbytes = (size_t)NN * NUM_FEAT * sizeof(float);   // 76.8 MB
    float* bufA = (float*)d_ws;
    float* bufB = (float*)((char*)d_ws + fbytes);

    const int total4  = NN * NUM_FEAT / 4;            // 4.8M
    const int blocks4 = (total4 + 255) / 256;         // 18750
    const int blocksE = (NUM_EDGES * 64 + 255) / 256; // 250000

    concat_init<<<blocks4, 256, 0, stream>>>(user, item, (float4*)bufA, (float4*)acc);

    float* feat = bufA;
    float* next = bufB;
    for (int layer = 0; layer < 3; ++layer) {
        hipMemsetAsync(next, 0, fbytes, stream);
        spmm_atomic<<<blocksE, 256, 0, stream>>>(rows, cols, vals, feat, next);
        acc_add<<<blocks4, 256, 0, stream>>>((float4*)acc, (const float4*)next);
        float* tmp = feat; feat = next; next = tmp;
    }
}

// Round 2
// 472.376 us; speedup vs baseline: 1.7474x; 1.7474x over previous
//
#include <hip/hip_runtime.h>

#define NU 100000
#define NI 200000
#define NF 64
#define NE 1000000
#define NN 300000            // NU + NI
#define SCAN_CHUNK 1024
#define NBLK ((NN + SCAN_CHUNK - 1) / SCAN_CHUNK)   // 293

// ---------- 1. histogram: counts[r] = #edges with row r ----------
__global__ void hist_kernel(const int* __restrict__ rows, int* __restrict__ counts) {
    int e = blockIdx.x * blockDim.x + threadIdx.x;
    if (e < NE) atomicAdd(&counts[rows[e]], 1);
}

// ---------- 2a. per-chunk exclusive scan (1024 elems / block) ----------
__global__ void scan_blocks(const int* __restrict__ counts, int* __restrict__ starts,
                            int* __restrict__ bsums) {
    __shared__ int lds[256];
    int base = blockIdx.x * SCAN_CHUNK;
    int t = threadIdx.x;
    int v[4]; int s = 0;
    #pragma unroll
    for (int j = 0; j < 4; ++j) {
        int idx = base + t * 4 + j;
        v[j] = (idx < NN) ? counts[idx] : 0;
        s += v[j];
    }
    lds[t] = s; __syncthreads();
    for (int off = 1; off < 256; off <<= 1) {
        int x = lds[t];
        int y = (t >= off) ? lds[t - off] : 0;
        __syncthreads();
        lds[t] = x + y;
        __syncthreads();
    }
    if (t == 255) bsums[blockIdx.x] = lds[255];
    int run = (t > 0) ? lds[t - 1] : 0;
    #pragma unroll
    for (int j = 0; j < 4; ++j) {
        int idx = base + t * 4 + j;
        if (idx < NN) starts[idx] = run;
        run += v[j];
    }
}

// ---------- 2b. scan the 293 block sums (exclusive, in place) ----------
__global__ void scan_sums(int* __restrict__ bsums) {
    __shared__ int lds[512];
    int t = threadIdx.x;
    lds[t] = (t < NBLK) ? bsums[t] : 0;
    __syncthreads();
    for (int off = 1; off < 512; off <<= 1) {
        int x = lds[t];
        int y = (t >= off) ? lds[t - off] : 0;
        __syncthreads();
        lds[t] = x + y;
        __syncthreads();
    }
    if (t < NBLK) bsums[t] = (t > 0) ? lds[t - 1] : 0;
}

// ---------- 2c. add chunk offsets; init cursor = start ----------
__global__ void scan_add(int* __restrict__ starts, const int* __restrict__ bsums,
                         int* __restrict__ cursor) {
    int i = blockIdx.x * blockDim.x + threadIdx.x;
    if (i >= NN) return;
    int s = starts[i] + bsums[i / SCAN_CHUNK];
    starts[i] = s;
    cursor[i] = s;
}

// ---------- 3. scatter edges into CSR order ----------
__global__ void scatter_kernel(const int* __restrict__ rows, const int* __restrict__ cols,
                               const float* __restrict__ vals, int* __restrict__ cursor,
                               int* __restrict__ scol, float* __restrict__ sval) {
    int e = blockIdx.x * blockDim.x + threadIdx.x;
    if (e >= NE) return;
    int r = rows[e];
    int p = atomicAdd(&cursor[r], 1);
    scol[p] = cols[e];
    sval[p] = vals[e];
}

// ---------- 4. SpMM: one wave per row, lane = feature ----------
// MODE 0: layer 1 — gather from user/item, acc = feat0 + sum, write featout
// MODE 1: layer 2 — gather featin, acc += sum, write featout
// MODE 2: layer 3 — gather featin, acc += sum, no featout
template <int MODE>
__global__ void spmm_csr(const int* __restrict__ starts, const int* __restrict__ ends,
                         const int* __restrict__ scol, const float* __restrict__ sval,
                         const float* __restrict__ featin,
                         const float* __restrict__ user, const float* __restrict__ item,
                         float* __restrict__ featout, float* __restrict__ acc) {
    int wid = __builtin_amdgcn_readfirstlane(
        (int)((blockIdx.x * blockDim.x + threadIdx.x) >> 6));
    if (wid >= NN) return;
    int f = threadIdx.x & 63;
    int s = starts[wid];
    int e = ends[wid];     // cursor after scatter == start + count
    float sum = 0.f;
    for (int k = s; k < e; ++k) {
        int   c = scol[k];
        float v = sval[k];
        const float* src;
        if (MODE == 0) src = (c < NU) ? (user + (size_t)c * NF)
                                      : (item + (size_t)(c - NU) * NF);
        else           src = featin + (size_t)c * NF;
        sum += v * src[f];
    }
    size_t o = (size_t)wid * NF + f;
    if (MODE == 0) {
        float base = (wid < NU) ? user[(size_t)wid * NF + f]
                                : item[(size_t)(wid - NU) * NF + f];
        acc[o] = base + sum;
        featout[o] = sum;
    } else if (MODE == 1) {
        acc[o] += sum;
        featout[o] = sum;
    } else {
        acc[o] += sum;
    }
}

extern "C" void kernel_launch(void* const* d_in, const int* in_sizes, int n_in,
                              void* d_out, int out_size, void* d_ws, size_t ws_size,
                              hipStream_t stream) {
    const float* user = (const float*)d_in[0];
    const float* item = (const float*)d_in[1];
    const int*   rows = (const int*)d_in[2];
    const int*   cols = (const int*)d_in[3];
    const float* vals = (const float*)d_in[4];
    float* acc = (float*)d_out;

    const size_t FB = (size_t)NN * NF * sizeof(float);   // 76.8 MB
    char* w = (char*)d_ws;
    float* feat1  = (float*)(w);
    float* feat2  = (float*)(w + FB);
    int*   scol   = (int*)  (w + 2 * FB);
    float* sval   = (float*)(w + 2 * FB + (size_t)NE * 4);
    int*   starts = (int*)  (w + 2 * FB + (size_t)NE * 8);
    int*   cursor = (int*)  (w + 2 * FB + (size_t)NE * 8 + (size_t)NN * 4);
    int*   bsums  = (int*)  (w + 2 * FB + (size_t)NE * 8 + (size_t)NN * 8);

    const int blocksE = (NE + 255) / 256;        // 3907
    const int blocksN = (NN + 255) / 256;        // 1172
    const int blocksW = NN * 64 / 256;           // 75000

    // CSR build
    hipMemsetAsync(cursor, 0, (size_t)NN * 4, stream);   // cursor doubles as counts
    hist_kernel<<<blocksE, 256, 0, stream>>>(rows, cursor);
    scan_blocks<<<NBLK, 256, 0, stream>>>(cursor, starts, bsums);
    scan_sums<<<1, 512, 0, stream>>>(bsums);
    scan_add<<<blocksN, 256, 0, stream>>>(starts, bsums, cursor);
    scatter_kernel<<<blocksE, 256, 0, stream>>>(rows, cols, vals, cursor, scol, sval);

    // 3 fused SpMM layers (cursor now holds row ends)
    spmm_csr<0><<<blocksW, 256, 0, stream>>>(starts, cursor, scol, sval,
                                             nullptr, user, item, feat1, acc);
    spmm_csr<1><<<blocksW, 256, 0, stream>>>(starts, cursor, scol, sval,
                                             feat1, user, item, feat2, acc);
    spmm_csr<2><<<blocksW, 256, 0, stream>>>(starts, cursor, scol, sval,
                                             feat2, user, item, nullptr, acc);
}

// Round 3
// 418.306 us; speedup vs baseline: 1.9732x; 1.1293x over previous
//
#include <hip/hip_runtime.h>

#define NU 100000
#define NI 200000
#define NF 64
#define NE 1000000
#define NN 300000            // NU + NI
#define SCAN_CHUNK 1024
#define NBLK ((NN + SCAN_CHUNK - 1) / SCAN_CHUNK)   // 293

// ---------- 1. histogram: counts[r] = #edges with row r ----------
__global__ void hist_kernel(const int* __restrict__ rows, int* __restrict__ counts) {
    int e = blockIdx.x * blockDim.x + threadIdx.x;
    if (e < NE) atomicAdd(&counts[rows[e]], 1);
}

// ---------- 2a. per-chunk exclusive scan (1024 elems / block) ----------
__global__ void scan_blocks(const int* __restrict__ counts, int* __restrict__ starts,
                            int* __restrict__ bsums) {
    __shared__ int lds[256];
    int base = blockIdx.x * SCAN_CHUNK;
    int t = threadIdx.x;
    int v[4]; int s = 0;
    #pragma unroll
    for (int j = 0; j < 4; ++j) {
        int idx = base + t * 4 + j;
        v[j] = (idx < NN) ? counts[idx] : 0;
        s += v[j];
    }
    lds[t] = s; __syncthreads();
    for (int off = 1; off < 256; off <<= 1) {
        int x = lds[t];
        int y = (t >= off) ? lds[t - off] : 0;
        __syncthreads();
        lds[t] = x + y;
        __syncthreads();
    }
    if (t == 255) bsums[blockIdx.x] = lds[255];
    int run = (t > 0) ? lds[t - 1] : 0;
    #pragma unroll
    for (int j = 0; j < 4; ++j) {
        int idx = base + t * 4 + j;
        if (idx < NN) starts[idx] = run;
        run += v[j];
    }
}

// ---------- 2b. scan the 293 block sums (exclusive, in place) ----------
__global__ void scan_sums(int* __restrict__ bsums) {
    __shared__ int lds[512];
    int t = threadIdx.x;
    lds[t] = (t < NBLK) ? bsums[t] : 0;
    __syncthreads();
    for (int off = 1; off < 512; off <<= 1) {
        int x = lds[t];
        int y = (t >= off) ? lds[t - off] : 0;
        __syncthreads();
        lds[t] = x + y;
        __syncthreads();
    }
    if (t < NBLK) bsums[t] = (t > 0) ? lds[t - 1] : 0;
}

// ---------- 2c. add chunk offsets; init cursor = start ----------
__global__ void scan_add(int* __restrict__ starts, const int* __restrict__ bsums,
                         int* __restrict__ cursor) {
    int i = blockIdx.x * blockDim.x + threadIdx.x;
    if (i >= NN) return;
    int s = starts[i] + bsums[i / SCAN_CHUNK];
    starts[i] = s;
    cursor[i] = s;
}

// ---------- 3. scatter edges into CSR order, packed (col, val) ----------
__global__ void scatter_kernel(const int* __restrict__ rows, const int* __restrict__ cols,
                               const float* __restrict__ vals, int* __restrict__ cursor,
                               int2* __restrict__ edges) {
    int e = blockIdx.x * blockDim.x + threadIdx.x;
    if (e >= NE) return;
    int r = rows[e];
    int p = atomicAdd(&cursor[r], 1);
    edges[p] = make_int2(cols[e], __float_as_int(vals[e]));
}

// ---------- 4. SpMM: one wave per row; 4 edges in flight (16 lanes x float4 each) ----------
// MODE 0: layer 1 — gather user/item, acc = base + sum, write featout
// MODE 1: layer 2 — gather featin, acc += sum, write featout
// MODE 2: layer 3 — gather featin, acc += sum, no featout
template <int MODE>
__global__ void spmm_csr4(const int* __restrict__ starts, const int* __restrict__ ends,
                          const int2* __restrict__ edges,
                          const float4* __restrict__ featin,
                          const float4* __restrict__ user4, const float4* __restrict__ item4,
                          float4* __restrict__ featout, float4* __restrict__ acc) {
    int wid = __builtin_amdgcn_readfirstlane(
        (int)((blockIdx.x * blockDim.x + threadIdx.x) >> 6));
    if (wid >= NN) return;
    int lane = threadIdx.x & 63;
    int g  = lane >> 4;     // which edge within a quad
    int fl = lane & 15;     // which float4 of the 64-feature row
    int s = starts[wid];
    int e = ends[wid];
    float4 sum = make_float4(0.f, 0.f, 0.f, 0.f);
    for (int k = s + g; k < e; k += 4) {
        int2  ed = edges[k];
        int   c  = ed.x;
        float v  = __int_as_float(ed.y);
        float4 x;
        if (MODE == 0) x = (c < NU) ? user4[(size_t)c * 16 + fl]
                                    : item4[(size_t)(c - NU) * 16 + fl];
        else           x = featin[(size_t)c * 16 + fl];
        sum.x += v * x.x; sum.y += v * x.y; sum.z += v * x.z; sum.w += v * x.w;
    }
    // reduce the 4 edge-groups (lanes differing in bits 4,5)
    sum.x += __shfl_xor(sum.x, 16); sum.y += __shfl_xor(sum.y, 16);
    sum.z += __shfl_xor(sum.z, 16); sum.w += __shfl_xor(sum.w, 16);
    sum.x += __shfl_xor(sum.x, 32); sum.y += __shfl_xor(sum.y, 32);
    sum.z += __shfl_xor(sum.z, 32); sum.w += __shfl_xor(sum.w, 32);
    if (g == 0) {
        size_t o = (size_t)wid * 16 + fl;
        if (MODE == 0) {
            float4 b = (wid < NU) ? user4[(size_t)wid * 16 + fl]
                                  : item4[(size_t)(wid - NU) * 16 + fl];
            b.x += sum.x; b.y += sum.y; b.z += sum.z; b.w += sum.w;
            acc[o] = b;
            featout[o] = sum;
        } else if (MODE == 1) {
            float4 a = acc[o];
            a.x += sum.x; a.y += sum.y; a.z += sum.z; a.w += sum.w;
            acc[o] = a;
            featout[o] = sum;
        } else {
            float4 a = acc[o];
            a.x += sum.x; a.y += sum.y; a.z += sum.z; a.w += sum.w;
            acc[o] = a;
        }
    }
}

extern "C" void kernel_launch(void* const* d_in, const int* in_sizes, int n_in,
                              void* d_out, int out_size, void* d_ws, size_t ws_size,
                              hipStream_t stream) {
    const float* user = (const float*)d_in[0];
    const float* item = (const float*)d_in[1];
    const int*   rows = (const int*)d_in[2];
    const int*   cols = (const int*)d_in[3];
    const float* vals = (const float*)d_in[4];
    float* acc = (float*)d_out;

    const size_t FB = (size_t)NN * NF * sizeof(float);   // 76.8 MB
    char* w = (char*)d_ws;
    float* feat1  = (float*)(w);
    float* feat2  = (float*)(w + FB);
    int2*  edges  = (int2*) (w + 2 * FB);
    int*   starts = (int*)  (w + 2 * FB + (size_t)NE * 8);
    int*   cursor = (int*)  (w + 2 * FB + (size_t)NE * 8 + (size_t)NN * 4);
    int*   bsums  = (int*)  (w + 2 * FB + (size_t)NE * 8 + (size_t)NN * 8);

    const int blocksE = (NE + 255) / 256;        // 3907
    const int blocksN = (NN + 255) / 256;        // 1172
    const int blocksW = NN * 64 / 256;           // 75000

    // CSR build
    hipMemsetAsync(cursor, 0, (size_t)NN * 4, stream);   // cursor doubles as counts
    hist_kernel<<<blocksE, 256, 0, stream>>>(rows, cursor);
    scan_blocks<<<NBLK, 256, 0, stream>>>(cursor, starts, bsums);
    scan_sums<<<1, 512, 0, stream>>>(bsums);
    scan_add<<<blocksN, 256, 0, stream>>>(starts, bsums, cursor);
    scatter_kernel<<<blocksE, 256, 0, stream>>>(rows, cols, vals, cursor, edges);

    // 3 fused SpMM layers (cursor now holds row ends)
    spmm_csr4<0><<<blocksW, 256, 0, stream>>>(starts, cursor, edges,
                                              nullptr, (const float4*)user,
                                              (const float4*)item,
                                              (float4*)feat1, (float4*)acc);
    spmm_csr4<1><<<blocksW, 256, 0, stream>>>(starts, cursor, edges,
                                              (const float4*)feat1, (const float4*)user,
                                              (const float4*)item,
                                              (float4*)feat2, (float4*)acc);
    spmm_csr4<2><<<blocksW, 256, 0, stream>>>(starts, cursor, edges,
                                              (const float4*)feat2, (const float4*)user,
                                              (const float4*)item,
                                              nullptr, (float4*)acc);
}

// Round 4
// 409.804 us; speedup vs baseline: 2.0142x; 1.0207x over previous
//
#include <hip/hip_runtime.h>

#define NU 100000
#define NI 200000
#define NF 64
#define NE 1000000
#define NN 300000            // NU + NI
#define SCAN_CHUNK 1024
#define NBLK ((NN + SCAN_CHUNK - 1) / SCAN_CHUNK)   // 293

// ---------- bf16 helpers (packed 2-per-uint) ----------
__device__ __forceinline__ unsigned bf16_rne(float f) {
    unsigned u = __float_as_uint(f);
    return (u + 0x7FFFu + ((u >> 16) & 1u)) >> 16;
}
__device__ __forceinline__ unsigned pack2(float lo, float hi) {
    return bf16_rne(lo) | (bf16_rne(hi) << 16);
}
__device__ __forceinline__ float blo(unsigned q) { return __uint_as_float(q << 16); }
__device__ __forceinline__ float bhi(unsigned q) { return __uint_as_float(q & 0xFFFF0000u); }

// ---------- 0. convert concat(user,item) fp32 -> bf16 table ----------
__global__ void f0_to_bf16(const float4* __restrict__ user4,
                           const float4* __restrict__ item4,
                           uint4* __restrict__ f0b) {
    int i = blockIdx.x * blockDim.x + threadIdx.x;      // one uint4 (8 feats) each
    if (i >= NN * 8) return;
    size_t fi = (size_t)i * 2;                          // concat float4 index
    const size_t ub = (size_t)NU * 16;
    float4 a = (fi < ub) ? user4[fi] : item4[fi - ub];
    float4 b = (fi + 1 < ub) ? user4[fi + 1] : item4[fi + 1 - ub];
    uint4 o;
    o.x = pack2(a.x, a.y); o.y = pack2(a.z, a.w);
    o.z = pack2(b.x, b.y); o.w = pack2(b.z, b.w);
    f0b[i] = o;
}

// ---------- 1. histogram ----------
__global__ void hist_kernel(const int* __restrict__ rows, int* __restrict__ counts) {
    int e = blockIdx.x * blockDim.x + threadIdx.x;
    if (e < NE) atomicAdd(&counts[rows[e]], 1);
}

// ---------- 2a. per-chunk exclusive scan ----------
__global__ void scan_blocks(const int* __restrict__ counts, int* __restrict__ starts,
                            int* __restrict__ bsums) {
    __shared__ int lds[256];
    int base = blockIdx.x * SCAN_CHUNK;
    int t = threadIdx.x;
    int v[4]; int s = 0;
    #pragma unroll
    for (int j = 0; j < 4; ++j) {
        int idx = base + t * 4 + j;
        v[j] = (idx < NN) ? counts[idx] : 0;
        s += v[j];
    }
    lds[t] = s; __syncthreads();
    for (int off = 1; off < 256; off <<= 1) {
        int x = lds[t];
        int y = (t >= off) ? lds[t - off] : 0;
        __syncthreads();
        lds[t] = x + y;
        __syncthreads();
    }
    if (t == 255) bsums[blockIdx.x] = lds[255];
    int run = (t > 0) ? lds[t - 1] : 0;
    #pragma unroll
    for (int j = 0; j < 4; ++j) {
        int idx = base + t * 4 + j;
        if (idx < NN) starts[idx] = run;
        run += v[j];
    }
}

// ---------- 2b. scan block sums ----------
__global__ void scan_sums(int* __restrict__ bsums) {
    __shared__ int lds[512];
    int t = threadIdx.x;
    lds[t] = (t < NBLK) ? bsums[t] : 0;
    __syncthreads();
    for (int off = 1; off < 512; off <<= 1) {
        int x = lds[t];
        int y = (t >= off) ? lds[t - off] : 0;
        __syncthreads();
        lds[t] = x + y;
        __syncthreads();
    }
    if (t < NBLK) bsums[t] = (t > 0) ? lds[t - 1] : 0;
}

// ---------- 2c. add offsets; cursor = start ----------
__global__ void scan_add(int* __restrict__ starts, const int* __restrict__ bsums,
                         int* __restrict__ cursor) {
    int i = blockIdx.x * blockDim.x + threadIdx.x;
    if (i >= NN) return;
    int s = starts[i] + bsums[i / SCAN_CHUNK];
    starts[i] = s;
    cursor[i] = s;
}

// ---------- 3. scatter (col,val) into CSR order ----------
__global__ void scatter_kernel(const int* __restrict__ rows, const int* __restrict__ cols,
                               const float* __restrict__ vals, int* __restrict__ cursor,
                               int2* __restrict__ edges) {
    int e = blockIdx.x * blockDim.x + threadIdx.x;
    if (e >= NE) return;
    int r = rows[e];
    int p = atomicAdd(&cursor[r], 1);
    edges[p] = make_int2(cols[e], __float_as_int(vals[e]));
}

// ---------- 4. SpMM: one wave/row, 8 edges in flight, bf16 gather ----------
// MODE 0: acc = base(fp32) + sum, write foutb
// MODE 1: acc += sum, write foutb
// MODE 2: acc += sum
template <int MODE>
__global__ void spmm_bf8(const int* __restrict__ starts, const int* __restrict__ ends,
                         const int2* __restrict__ edges,
                         const uint4* __restrict__ gtab,
                         const float4* __restrict__ user4, const float4* __restrict__ item4,
                         uint4* __restrict__ foutb, float4* __restrict__ acc) {
    int wid = (int)((blockIdx.x * (size_t)blockDim.x + threadIdx.x) >> 6);
    if (wid >= NN) return;
    int lane = threadIdx.x & 63;
    int g = lane >> 3;      // edge group 0..7
    int j = lane & 7;       // 16B chunk (8 feats) within row
    int s = starts[wid];
    int e = ends[wid];
    float sum[8];
    #pragma unroll
    for (int t = 0; t < 8; ++t) sum[t] = 0.f;
    for (int k = s + g; k < e; k += 8) {
        int2  ed = edges[k];
        int   c  = ed.x;
        float v  = __int_as_float(ed.y);
        uint4 q  = gtab[(size_t)c * 8 + j];
        sum[0] += v * blo(q.x); sum[1] += v * bhi(q.x);
        sum[2] += v * blo(q.y); sum[3] += v * bhi(q.y);
        sum[4] += v * blo(q.z); sum[5] += v * bhi(q.z);
        sum[6] += v * blo(q.w); sum[7] += v * bhi(q.w);
    }
    // reduce across the 8 edge groups (lane bits 3,4,5)
    #pragma unroll
    for (int t = 0; t < 8; ++t) sum[t] += __shfl_xor(sum[t], 8);
    #pragma unroll
    for (int t = 0; t < 8; ++t) sum[t] += __shfl_xor(sum[t], 16);
    #pragma unroll
    for (int t = 0; t < 8; ++t) sum[t] += __shfl_xor(sum[t], 32);

    if (g == 0) {
        size_t r16 = (size_t)wid * 16 + j * 2;       // float4 index into acc
        float4 s0 = make_float4(sum[0], sum[1], sum[2], sum[3]);
        float4 s1 = make_float4(sum[4], sum[5], sum[6], sum[7]);
        float4 a0, a1;
        if (MODE == 0) {
            size_t bi = r16;
            if (wid < NU) { a0 = user4[bi]; a1 = user4[bi + 1]; }
            else { a0 = item4[bi - (size_t)NU * 16]; a1 = item4[bi + 1 - (size_t)NU * 16]; }
        } else {
            a0 = acc[r16]; a1 = acc[r16 + 1];
        }
        a0.x += s0.x; a0.y += s0.y; a0.z += s0.z; a0.w += s0.w;
        a1.x += s1.x; a1.y += s1.y; a1.z += s1.z; a1.w += s1.w;
        acc[r16] = a0; acc[r16 + 1] = a1;
        if (MODE != 2) {
            uint4 o;
            o.x = pack2(sum[0], sum[1]); o.y = pack2(sum[2], sum[3]);
            o.z = pack2(sum[4], sum[5]); o.w = pack2(sum[6], sum[7]);
            foutb[(size_t)wid * 8 + j] = o;
        }
    }
}

extern "C" void kernel_launch(void* const* d_in, const int* in_sizes, int n_in,
                              void* d_out, int out_size, void* d_ws, size_t ws_size,
                              hipStream_t stream) {
    const float* user = (const float*)d_in[0];
    const float* item = (const float*)d_in[1];
    const int*   rows = (const int*)d_in[2];
    const int*   cols = (const int*)d_in[3];
    const float* vals = (const float*)d_in[4];
    float* acc = (float*)d_out;

    const size_t TB = (size_t)NN * 8 * sizeof(uint4);    // bf16 table: 38.4 MB
    char* w = (char*)d_ws;
    uint4* f0b    = (uint4*)(w);
    uint4* f1b    = (uint4*)(w + TB);
    uint4* f2b    = (uint4*)(w + 2 * TB);
    int2*  edges  = (int2*) (w + 3 * TB);
    int*   starts = (int*)  (w + 3 * TB + (size_t)NE * 8);
    int*   cursor = (int*)  (w + 3 * TB + (size_t)NE * 8 + (size_t)NN * 4);
    int*   bsums  = (int*)  (w + 3 * TB + (size_t)NE * 8 + (size_t)NN * 8);

    const int blocksE = (NE + 255) / 256;        // 3907
    const int blocksN = (NN + 255) / 256;        // 1172
    const int blocksC = (NN * 8 + 255) / 256;    // 9375
    const int blocksW = NN * 64 / 256;           // 75000

    // CSR build + bf16 base table
    hipMemsetAsync(cursor, 0, (size_t)NN * 4, stream);
    hist_kernel<<<blocksE, 256, 0, stream>>>(rows, cursor);
    scan_blocks<<<NBLK, 256, 0, stream>>>(cursor, starts, bsums);
    scan_sums<<<1, 512, 0, stream>>>(bsums);
    scan_add<<<blocksN, 256, 0, stream>>>(starts, bsums, cursor);
    scatter_kernel<<<blocksE, 256, 0, stream>>>(rows, cols, vals, cursor, edges);
    f0_to_bf16<<<blocksC, 256, 0, stream>>>((const float4*)user, (const float4*)item, f0b);

    // 3 fused SpMM layers (cursor now holds row ends)
    spmm_bf8<0><<<blocksW, 256, 0, stream>>>(starts, cursor, edges, f0b,
                                             (const float4*)user, (const float4*)item,
                                             f1b, (float4*)acc);
    spmm_bf8<1><<<blocksW, 256, 0, stream>>>(starts, cursor, edges, f1b,
                                             (const float4*)user, (const float4*)item,
                                             f2b, (float4*)acc);
    spmm_bf8<2><<<blocksW, 256, 0, stream>>>(starts, cursor, edges, f2b,
                                             (const float4*)user, (const float4*)item,
                                             nullptr, (float4*)acc);
}

// Round 5
// 258.408 us; speedup vs baseline: 3.1942x; 1.5859x over previous
//
#include <hip/hip_runtime.h>
#include <hip/hip_fp16.h>

#define NU 100000
#define NI 200000
#define NF 64
#define NE 1000000
#define NN 300000            // NU + NI
#define SCAN_CHUNK 1024
#define NBLK ((NN + SCAN_CHUNK - 1) / SCAN_CHUNK)   // 293

// ---------- fp16 helpers (8 halves in a uint4) ----------
__device__ __forceinline__ void fma8(float sum[8], float v, uint4 q) {
    union { uint4 u; __half2 h[4]; } c; c.u = q;
    #pragma unroll
    for (int i = 0; i < 4; ++i) {
        float2 f = __half22float2(c.h[i]);
        sum[2 * i]     = fmaf(v, f.x, sum[2 * i]);
        sum[2 * i + 1] = fmaf(v, f.y, sum[2 * i + 1]);
    }
}
__device__ __forceinline__ uint4 pack8(const float sum[8]) {
    union { uint4 u; __half2 h[4]; } c;
    #pragma unroll
    for (int i = 0; i < 4; ++i)
        c.h[i] = __float22half2_rn(make_float2(sum[2 * i], sum[2 * i + 1]));
    return c.u;
}
__device__ __forceinline__ void add8(float4& a0, float4& a1, uint4 q) {
    union { uint4 u; __half2 h[4]; } c; c.u = q;
    float2 f0 = __half22float2(c.h[0]);
    float2 f1 = __half22float2(c.h[1]);
    float2 f2 = __half22float2(c.h[2]);
    float2 f3 = __half22float2(c.h[3]);
    a0.x += f0.x; a0.y += f0.y; a0.z += f1.x; a0.w += f1.y;
    a1.x += f2.x; a1.y += f2.y; a1.z += f3.x; a1.w += f3.y;
}

// ---------- 0. convert concat(user,item) fp32 -> fp16 table ----------
__global__ void f0_to_h(const float4* __restrict__ user4,
                        const float4* __restrict__ item4,
                        uint4* __restrict__ f0h) {
    int i = blockIdx.x * blockDim.x + threadIdx.x;      // one uint4 (8 feats) each
    if (i >= NN * 8) return;
    size_t fi = (size_t)i * 2;
    const size_t ub = (size_t)NU * 16;
    float4 a = (fi < ub) ? user4[fi] : item4[fi - ub];
    float4 b = (fi + 1 < ub) ? user4[fi + 1] : item4[fi + 1 - ub];
    float s[8] = { a.x, a.y, a.z, a.w, b.x, b.y, b.z, b.w };
    f0h[i] = pack8(s);
}

// ---------- 1. histogram ----------
__global__ void hist_kernel(const int* __restrict__ rows, int* __restrict__ counts) {
    int e = blockIdx.x * blockDim.x + threadIdx.x;
    if (e < NE) atomicAdd(&counts[rows[e]], 1);
}

// ---------- 2a. per-chunk exclusive scan ----------
__global__ void scan_blocks(const int* __restrict__ counts, int* __restrict__ starts,
                            int* __restrict__ bsums) {
    __shared__ int lds[256];
    int base = blockIdx.x * SCAN_CHUNK;
    int t = threadIdx.x;
    int v[4]; int s = 0;
    #pragma unroll
    for (int j = 0; j < 4; ++j) {
        int idx = base + t * 4 + j;
        v[j] = (idx < NN) ? counts[idx] : 0;
        s += v[j];
    }
    lds[t] = s; __syncthreads();
    for (int off = 1; off < 256; off <<= 1) {
        int x = lds[t];
        int y = (t >= off) ? lds[t - off] : 0;
        __syncthreads();
        lds[t] = x + y;
        __syncthreads();
    }
    if (t == 255) bsums[blockIdx.x] = lds[255];
    int run = (t > 0) ? lds[t - 1] : 0;
    #pragma unroll
    for (int j = 0; j < 4; ++j) {
        int idx = base + t * 4 + j;
        if (idx < NN) starts[idx] = run;
        run += v[j];
    }
}

// ---------- 2b. scan block sums ----------
__global__ void scan_sums(int* __restrict__ bsums) {
    __shared__ int lds[512];
    int t = threadIdx.x;
    lds[t] = (t < NBLK) ? bsums[t] : 0;
    __syncthreads();
    for (int off = 1; off < 512; off <<= 1) {
        int x = lds[t];
        int y = (t >= off) ? lds[t - off] : 0;
        __syncthreads();
        lds[t] = x + y;
        __syncthreads();
    }
    if (t < NBLK) bsums[t] = (t > 0) ? lds[t - 1] : 0;
}

// ---------- 2c. add offsets; cursor = start ----------
__global__ void scan_add(int* __restrict__ starts, const int* __restrict__ bsums,
                         int* __restrict__ cursor) {
    int i = blockIdx.x * blockDim.x + threadIdx.x;
    if (i >= NN) return;
    int s = starts[i] + bsums[i / SCAN_CHUNK];
    starts[i] = s;
    cursor[i] = s;
}

// ---------- 3. scatter (col,val) into CSR order ----------
__global__ void scatter_kernel(const int* __restrict__ rows, const int* __restrict__ cols,
                               const float* __restrict__ vals, int* __restrict__ cursor,
                               int2* __restrict__ edges) {
    int e = blockIdx.x * blockDim.x + threadIdx.x;
    if (e >= NE) return;
    int r = rows[e];
    int p = atomicAdd(&cursor[r], 1);
    edges[p] = make_int2(cols[e], __float_as_int(vals[e]));
}

// ---------- 4. SpMM: 8 lanes per row, serial edges, no shuffles ----------
// MODE 0/1: write fout (fp16 table) only.
// MODE 2:   acc = base(fp32) + f1 + f2 + sum   (no fout)
template <int MODE>
__global__ void spmm_row8(const int* __restrict__ starts, const int* __restrict__ ends,
                          const int2* __restrict__ edges, const uint4* __restrict__ gtab,
                          uint4* __restrict__ fout,
                          const uint4* __restrict__ f1h, const uint4* __restrict__ f2h,
                          const float4* __restrict__ user4, const float4* __restrict__ item4,
                          float4* __restrict__ acc) {
    int tid = blockIdx.x * blockDim.x + threadIdx.x;
    int row = tid >> 3;          // 8 rows per wave
    if (row >= NN) return;
    int j = tid & 7;             // which 16B chunk (8 feats) of the row
    int s = starts[row];
    int e = ends[row];
    float sum[8];
    #pragma unroll
    for (int t = 0; t < 8; ++t) sum[t] = 0.f;
    if (s < e) {
        int2 ed = edges[s];
        for (int k = s; k < e; ++k) {
            int2 nxt = ed;
            if (k + 1 < e) nxt = edges[k + 1];     // prefetch next edge record
            uint4 q = gtab[(size_t)ed.x * 8 + j];  // 128B row gather, 16B/lane
            fma8(sum, __int_as_float(ed.y), q);
            ed = nxt;
        }
    }
    if (MODE != 2) {
        fout[(size_t)row * 8 + j] = pack8(sum);
    } else {
        size_t r16 = (size_t)row * 16 + (size_t)j * 2;
        float4 a0, a1;
        if (row < NU) { a0 = user4[r16]; a1 = user4[r16 + 1]; }
        else {
            size_t bi = r16 - (size_t)NU * 16;
            a0 = item4[bi]; a1 = item4[bi + 1];
        }
        a0.x += sum[0]; a0.y += sum[1]; a0.z += sum[2]; a0.w += sum[3];
        a1.x += sum[4]; a1.y += sum[5]; a1.z += sum[6]; a1.w += sum[7];
        size_t t8 = (size_t)row * 8 + j;
        add8(a0, a1, f1h[t8]);
        add8(a0, a1, f2h[t8]);
        acc[r16] = a0; acc[r16 + 1] = a1;
    }
}

extern "C" void kernel_launch(void* const* d_in, const int* in_sizes, int n_in,
                              void* d_out, int out_size, void* d_ws, size_t ws_size,
                              hipStream_t stream) {
    const float* user = (const float*)d_in[0];
    const float* item = (const float*)d_in[1];
    const int*   rows = (const int*)d_in[2];
    const int*   cols = (const int*)d_in[3];
    const float* vals = (const float*)d_in[4];
    float* acc = (float*)d_out;

    const size_t TB = (size_t)NN * 8 * sizeof(uint4);    // fp16 table: 38.4 MB
    char* w = (char*)d_ws;
    uint4* f0h    = (uint4*)(w);
    uint4* f1h    = (uint4*)(w + TB);
    uint4* f2h    = (uint4*)(w + 2 * TB);
    int2*  edges  = (int2*) (w + 3 * TB);
    int*   starts = (int*)  (w + 3 * TB + (size_t)NE * 8);
    int*   cursor = (int*)  (w + 3 * TB + (size_t)NE * 8 + (size_t)NN * 4);
    int*   bsums  = (int*)  (w + 3 * TB + (size_t)NE * 8 + (size_t)NN * 8);

    const int blocksE = (NE + 255) / 256;        // 3907
    const int blocksN = (NN + 255) / 256;        // 1172
    const int blocksC = (NN * 8 + 255) / 256;    // 9375
    const int blocksR = (NN * 8 + 255) / 256;    // 9375  (8 lanes/row)

    // CSR build + fp16 base table
    hipMemsetAsync(cursor, 0, (size_t)NN * 4, stream);
    hist_kernel<<<blocksE, 256, 0, stream>>>(rows, cursor);
    scan_blocks<<<NBLK, 256, 0, stream>>>(cursor, starts, bsums);
    scan_sums<<<1, 512, 0, stream>>>(bsums);
    scan_add<<<blocksN, 256, 0, stream>>>(starts, bsums, cursor);
    scatter_kernel<<<blocksE, 256, 0, stream>>>(rows, cols, vals, cursor, edges);
    f0_to_h<<<blocksC, 256, 0, stream>>>((const float4*)user, (const float4*)item, f0h);

    // 3 SpMM layers (cursor holds row ends); acc only touched in layer 3
    spmm_row8<0><<<blocksR, 256, 0, stream>>>(starts, cursor, edges, f0h,
                                              f1h, nullptr, nullptr,
                                              nullptr, nullptr, nullptr);
    spmm_row8<1><<<blocksR, 256, 0, stream>>>(starts, cursor, edges, f1h,
                                              f2h, nullptr, nullptr,
                                              nullptr, nullptr, nullptr);
    spmm_row8<2><<<blocksR, 256, 0, stream>>>(starts, cursor, edges, f2h,
                                              nullptr, f1h, f2h,
                                              (const float4*)user, (const float4*)item,
                                              (float4*)acc);
}